// Round 14
// baseline (402.080 us; speedup 1.0000x reference)
//
#include <hip/hip_runtime.h>
#include <hip/hip_bf16.h>
#include <math.h>

typedef __bf16 bf16x8 __attribute__((ext_vector_type(8)));
typedef float f32x4 __attribute__((ext_vector_type(4)));
typedef unsigned short u16x8 __attribute__((ext_vector_type(8)));
typedef unsigned short u16x4 __attribute__((ext_vector_type(4)));
typedef unsigned short u16;

#define S_LEN 2048
#define DMODEL 1024
#define NH 16

__device__ __forceinline__ u16 f2bf(float f) {
    __bf16 b = (__bf16)f;
    return __builtin_bit_cast(u16, b);
}
__device__ __forceinline__ float bf2f(u16 u) {
    union { unsigned int i; float f; } v; v.i = ((unsigned int)u) << 16; return v.f;
}

// global -> LDS direct copy, 16B per lane (wave-uniform LDS base + lane*16).
__device__ __forceinline__ void gload16(const u16* g, u16* lds_base) {
    __builtin_amdgcn_global_load_lds(
        (const __attribute__((address_space(1))) unsigned int*)g,
        (__attribute__((address_space(3))) unsigned int*)lds_base,
        16, 0, 0);
}

// ---------- prep: blocks [0,4096) = X f32->bf16 ; blocks [4096,7168) = W transpose ----------
__global__ __launch_bounds__(256) void prep(const float* __restrict__ X, u16* __restrict__ Xb,
                                            const float* __restrict__ W, u16* __restrict__ Wt) {
    __shared__ u16 tile[32][33];
    const int bid = blockIdx.x;
    if (bid < 4096) {
        int i = (bid * 256 + threadIdx.x) * 4;
        float4 v = *(const float4*)(X + i);
        Xb[i + 0] = f2bf(v.x); Xb[i + 1] = f2bf(v.y);
        Xb[i + 2] = f2bf(v.z); Xb[i + 3] = f2bf(v.w);
    } else {
        int bid2 = bid - 4096;
        int n0 = (bid2 % 96) * 32, k0 = (bid2 / 96) * 32;
        int tx = threadIdx.x & 31, ty = threadIdx.x >> 5;
#pragma unroll
        for (int i = 0; i < 4; i++) {
            int k = ty + i * 8;
            tile[k][tx] = f2bf(W[(size_t)(k0 + k) * 3072 + n0 + tx]);
        }
        __syncthreads();
#pragma unroll
        for (int i = 0; i < 4; i++) {
            int n = ty + i * 8;
            Wt[(size_t)(n0 + n) * 1024 + k0 + tx] = tile[tx][n];
        }
    }
}

// ---------- QKV GEMM with fused V-transpose epilogue + XCD-chunked block remap ----------
__global__ __launch_bounds__(256) void qkv_gemm(const u16* __restrict__ A, const u16* __restrict__ Bt,
                                                u16* __restrict__ C, u16* __restrict__ Vtp) {
    __shared__ alignas(16) u16 As[128 * 64];
    __shared__ alignas(16) u16 Bs[128 * 64];
    const int tid = threadIdx.x, l = tid & 63, w = tid >> 6;
    // XCD-chunked remap: each XCD gets 3 consecutive bn columns x all 32 bm (B-slice 768KB L2-res)
    const int fid = blockIdx.x + blockIdx.y * 24;
    const int swz = (fid & 7) * 96 + (fid >> 3);   // bijective: 768 = 8*96
    const int bn = swz >> 5, bm = swz & 31;
    const int wm = w >> 1, wn = w & 1;
    const int c0 = l & 15, g = l >> 4;
    f32x4 acc[4][4] = {};
    for (int kt = 0; kt < 1024; kt += 64) {
        __syncthreads();
#pragma unroll
        for (int n = 0; n < 4; n++) {
            int i = tid + n * 256;
            int r = i >> 3, c = i & 7;
            int cs = c ^ (r & 7);
            u16* dstA = As + (size_t)(w * 64 + n * 256) * 8;
            u16* dstB = Bs + (size_t)(w * 64 + n * 256) * 8;
            gload16(A + (size_t)(bm * 128 + r) * 1024 + kt + cs * 8, dstA);
            gload16(Bt + (size_t)(bn * 128 + r) * 1024 + kt + cs * 8, dstB);
        }
        __syncthreads();
#pragma unroll
        for (int kk = 0; kk < 2; kk++) {
            bf16x8 af[4], bfr[4];
#pragma unroll
            for (int m = 0; m < 4; m++) {
                int row = wm * 64 + m * 16 + c0;
                af[m] = *(const bf16x8*)((const char*)As + row * 128 + (((g + kk * 4) ^ (row & 7)) << 4));
            }
#pragma unroll
            for (int n = 0; n < 4; n++) {
                int row = wn * 64 + n * 16 + c0;
                bfr[n] = *(const bf16x8*)((const char*)Bs + row * 128 + (((g + kk * 4) ^ (row & 7)) << 4));
            }
#pragma unroll
            for (int m = 0; m < 4; m++)
#pragma unroll
                for (int n = 0; n < 4; n++)
                    acc[m][n] = __builtin_amdgcn_mfma_f32_16x16x32_bf16(af[m], bfr[n], acc[m][n], 0, 0, 0);
        }
    }
    if (bn < 16) {
#pragma unroll
        for (int m = 0; m < 4; m++)
#pragma unroll
            for (int n = 0; n < 4; n++)
#pragma unroll
                for (int j = 0; j < 4; j++) {
                    int row = bm * 128 + wm * 64 + m * 16 + 4 * g + j;
                    int col = bn * 128 + wn * 64 + n * 16 + c0;
                    C[(size_t)row * 3072 + col] = f2bf(acc[m][n][j]);
                }
    } else {
        // V third: direct permuted-transpose store (4 consecutive spos per (m,n) -> 8B store)
        const int h = (bn - 16) * 2 + wn;
#pragma unroll
        for (int m = 0; m < 4; m++) {
            int srow_g = bm * 128 + wm * 64 + m * 16 + 4 * g;   // +j
            int b = srow_g >> 11;
            int srow = srow_g & 2047;
            int sbase = (srow & ~63) + 32 * (m >> 1) + 8 * g + 4 * (m & 1);
#pragma unroll
            for (int n = 0; n < 4; n++) {
                int d = n * 16 + c0;
                u16x4 v;
#pragma unroll
                for (int j = 0; j < 4; j++) v[j] = f2bf(acc[m][n][j]);
                *(u16x4*)(Vtp + ((size_t)(b * 16 + h) * 64 + d) * S_LEN + sbase) = v;
            }
        }
    }
}

// ---------- Flash attention v12: attn11 datapath with KVBLK=32 (32KB LDS -> 4 blocks/CU).
// 8 waves / 512 thr: waves 0-3 = KV half 0, waves 4-7 = half 1; in-LDS merge epilogue.
// K tile [32 key][64 d] rows 128B, chunk^=(key&7). V tile [64 d][32 pos] rows 64B,
// chunk^=((d>>1)&3) (2-way banked = free). Vtp perm is 32-granular so pf is lane-local. ----------
__global__ __launch_bounds__(512, 8) void attn12(const u16* __restrict__ QKV, const u16* __restrict__ Vtp,
                                                 float* __restrict__ outp) {
    __shared__ alignas(16) u16 smem[16384];   // 32KB: [0,8192) K: [hf][buf][2048]; [8192,16384) V
    const int bid = blockIdx.x;
    const int wg = ((bid & 7) << 7) | (bid >> 3);    // 1024 = 8*128, bijective XCD swizzle
    const int tid = threadIdx.x, l = tid & 63, w = tid >> 6;
    const int hf = w >> 2, wsub = w & 3;             // half & wave-within-half
    const int qt = wg & 31, bh = wg >> 5;
    const int b = bh >> 4, h = bh & 15;
    const int c0 = l & 15, g = l >> 4;
    const u16* Qb = QKV + (size_t)b * S_LEN * 3072 + h * 64;
    const u16* Kb = Qb + 1024;
    const u16* Vb = Vtp + (size_t)bh * 64 * S_LEN;
    const int kv0 = hf * 1024;
    const int qrow = qt * 64 + wsub * 16 + c0;

    // staging (per half, 256 threads, ONE chunk per thread per operand):
    // K: 32 rows x 8 chunks; V: 64 rows x 4 chunks
    const int tid_h = tid & 255;
    const int rK = tid_h >> 3, cK = (tid_h & 7) ^ (rK & 7);
    const int rV = tid_h >> 2, cV = (tid_h & 3) ^ ((rV >> 1) & 3);
    const int db = (wsub * 64) * 8;                  // wave-uniform dest offset (u16)
    u16* Kbase[2] = { smem + (hf * 2 + 0) * 2048, smem + (hf * 2 + 1) * 2048 };
    u16* Vbase[2] = { smem + 8192 + (hf * 2 + 0) * 2048, smem + 8192 + (hf * 2 + 1) * 2048 };

    // LDS read byte-offsets (loop-invariant)
    int koff[4], voff[4];
#pragma unroll
    for (int x = 0; x < 2; x++)
#pragma unroll
        for (int kk = 0; kk < 2; kk++)
            koff[x * 2 + kk] = (x * 16 + c0) * 128 + (((g + 4 * kk) ^ (c0 & 7)) << 4);
#pragma unroll
    for (int n = 0; n < 4; n++) {
        int d = n * 16 + c0;
        voff[n] = d * 64 + ((g ^ ((d >> 1) & 3)) << 4);
    }

    // Q B-frags; fold (1/8)*log2(e)
    bf16x8 qf[2];
    {
        const float qs = 0.125f * 1.44269504f;
#pragma unroll
        for (int kk = 0; kk < 2; kk++) {
            u16x8 v = *(const u16x8*)(Qb + (size_t)qrow * 3072 + kk * 32 + g * 8);
            bf16x8 q;
#pragma unroll
            for (int j = 0; j < 8; j++) q[j] = (__bf16)(bf2f(v[j]) * qs);
            qf[kk] = q;
        }
    }
    bf16x8 vone;
#pragma unroll
    for (int j = 0; j < 8; j++) vone[j] = (__bf16)1.0f;

    float m_r = 0.f;             // baked scheme: sc accumulates S - m_r (per-lane q = c0)
    f32x4 accO[4] = {};
    f32x4 accL = {};

    // prologue: stage tile 0 into buf 0
    gload16(Kb + (size_t)(kv0 + rK) * 3072 + cK * 8, Kbase[0] + db);
    gload16(Vb + (size_t)rV * S_LEN + kv0 + cV * 8, Vbase[0] + db);

    for (int t = 0; t < 32; t++) {
        const int cur = t & 1;
        __syncthreads();  // buf[cur] staged (vmcnt drained at barrier) + prev reads done
        if (t + 1 < 32) {
            const int kvn = kv0 + (t + 1) * 32;
            gload16(Kb + (size_t)(kvn + rK) * 3072 + cK * 8, Kbase[cur ^ 1] + db);
            gload16(Vb + (size_t)rV * S_LEN + kvn + cV * 8, Vbase[cur ^ 1] + db);
        }
        const char* Kc = (const char*)Kbase[cur];
        const char* Vc = (const char*)Vbase[cur];
        // QK^T (swapped) with C-in = -m_r: sc = S - m_r directly
        f32x4 sc[2];
        const float nm = -m_r;
#pragma unroll
        for (int kb = 0; kb < 2; kb++) { sc[kb][0] = nm; sc[kb][1] = nm; sc[kb][2] = nm; sc[kb][3] = nm; }
        __builtin_amdgcn_s_setprio(1);
#pragma unroll
        for (int kb = 0; kb < 2; kb++)
#pragma unroll
            for (int kk = 0; kk < 2; kk++) {
                bf16x8 kf = *(const bf16x8*)(Kc + koff[kb * 2 + kk]);
                sc[kb] = __builtin_amdgcn_mfma_f32_16x16x32_bf16(kf, qf[kk], sc[kb], 0, 0, 0);
            }
        __builtin_amdgcn_s_setprio(0);
        // V fragment reads (latency hides under softmax)
        bf16x8 vf[4];
#pragma unroll
        for (int n = 0; n < 4; n++)
            vf[n] = *(const bf16x8*)(Vc + voff[n]);
        // lane-local max of baked scores
        float m0 = fmaxf(fmaxf(sc[0][0], sc[0][1]), sc[0][2]);
        float m1 = fmaxf(fmaxf(sc[0][3], sc[1][0]), sc[1][1]);
        float mx = fmaxf(fmaxf(m0, m1), fmaxf(fmaxf(sc[1][2], sc[1][3]), 0.f) - 0.f);
        mx = fmaxf(mx, fmaxf(sc[1][2], sc[1][3]));
        // defer-max: rescale only if some lane's local growth exceeds 8 (log2 domain)
        if (!__all(mx <= 8.f)) {
            float mxr = fmaxf(mx, __shfl_xor(mx, 16));
            mxr = fmaxf(mxr, __shfl_xor(mxr, 32));        // per-q full-row baked max
            float adj = fmaxf(mxr, 0.f);
            float alpha = __builtin_amdgcn_exp2f(-adj);
            m_r += adj;
#pragma unroll
            for (int j = 0; j < 4; j++) {
                float aj = __shfl(alpha, 20 * g + j);
                accL[j] *= aj;
#pragma unroll
                for (int n = 0; n < 4; n++) accO[n][j] *= aj;
            }
#pragma unroll
            for (int kb = 0; kb < 2; kb++)
#pragma unroll
                for (int j = 0; j < 4; j++) sc[kb][j] -= adj;
        }
        // P = exp2(baked scores)
#pragma unroll
        for (int kb = 0; kb < 2; kb++)
#pragma unroll
            for (int j = 0; j < 4; j++)
                sc[kb][j] = __builtin_amdgcn_exp2f(sc[kb][j]);
        // PV + l (accL = P @ ones, rows match accO); pos_local = 8g + 4kb' + j -> pf lane-local
        __builtin_amdgcn_s_setprio(1);
        {
            bf16x8 pf;
#pragma unroll
            for (int j = 0; j < 4; j++) {
                pf[j]     = (__bf16)sc[0][j];
                pf[j + 4] = (__bf16)sc[1][j];
            }
            accL = __builtin_amdgcn_mfma_f32_16x16x32_bf16(pf, vone, accL, 0, 0, 0);
#pragma unroll
            for (int n = 0; n < 4; n++)
                accO[n] = __builtin_amdgcn_mfma_f32_16x16x32_bf16(pf, vf[n], accO[n], 0, 0, 0);
        }
        __builtin_amdgcn_s_setprio(0);
    }
    // ---- in-block merge: half-1 dumps unnormalized partials into (dead) smem ----
    __syncthreads();
    float* Opart = (float*)smem;             // 64 x 65 f32 = 16.6KB
    float* m1s   = Opart + 64 * 65;          // 64 f32
    float* l1s   = m1s + 64;                 // 64 f32 (total 17.2KB < 32KB)
    if (hf == 1) {
#pragma unroll
        for (int j = 0; j < 4; j++) {
            int rj = wsub * 16 + 4 * g + j;
#pragma unroll
            for (int n = 0; n < 4; n++) Opart[rj * 65 + n * 16 + c0] = accO[n][j];
        }
        if (g == 0) m1s[wsub * 16 + c0] = m_r;
        if (c0 == 0) {
#pragma unroll
            for (int j = 0; j < 4; j++) l1s[wsub * 16 + 4 * g + j] = accL[j];
        }
    }
    __syncthreads();
    if (hf == 0) {
#pragma unroll
        for (int j = 0; j < 4; j++) {
            int rj = wsub * 16 + 4 * g + j;
            float m1v = m1s[rj], l1v = l1s[rj];
            float m0v = __shfl(m_r, 20 * g + j);
            float M = fmaxf(m0v, m1v);
            float a0 = __builtin_amdgcn_exp2f(m0v - M);
            float a1 = __builtin_amdgcn_exp2f(m1v - M);
            float inv = 1.0f / (a0 * accL[j] + a1 * l1v);
            float* op = outp + ((size_t)b * S_LEN + qt * 64 + rj) * DMODEL + h * 64;
#pragma unroll
            for (int n = 0; n < 4; n++)
                op[n * 16 + c0] = (a0 * accO[n][j] + a1 * Opart[rj * 65 + n * 16 + c0]) * inv;
        }
    }
}

extern "C" void kernel_launch(void* const* d_in, const int* in_sizes, int n_in,
                              void* d_out, int out_size, void* d_ws, size_t ws_size,
                              hipStream_t stream) {
    const float* X = (const float*)d_in[0];
    const float* W = (const float*)d_in[1];
    float* out = (float*)d_out;

    u16* Xb  = (u16*)d_ws;                        // 4096*1024 bf16
    u16* Wt  = Xb + (size_t)4096 * 1024;          // 3072*1024 bf16
    u16* QKV = Wt + (size_t)3072 * 1024;          // 4096*3072 bf16 (V third unused)
    u16* Vtp = QKV + (size_t)4096 * 3072;         // 32*64*2048 bf16 (~48MB total)

    prep<<<7168, 256, 0, stream>>>(X, Xb, W, Wt);
    qkv_gemm<<<dim3(24, 32), 256, 0, stream>>>(Xb, Wt, QKV, Vtp);
    attn12<<<1024, 512, 0, stream>>>(QKV, Vtp, out);
}

// Round 15
// 122.957 us; speedup vs baseline: 3.2701x; 3.2701x over previous
//
#include <hip/hip_runtime.h>
#include <hip/hip_bf16.h>
#include <math.h>

typedef __bf16 bf16x8 __attribute__((ext_vector_type(8)));
typedef float f32x4 __attribute__((ext_vector_type(4)));
typedef unsigned short u16x8 __attribute__((ext_vector_type(8)));
typedef unsigned short u16x4 __attribute__((ext_vector_type(4)));
typedef unsigned short u16;

#define S_LEN 2048
#define DMODEL 1024
#define NH 16

__device__ __forceinline__ u16 f2bf(float f) {
    __bf16 b = (__bf16)f;
    return __builtin_bit_cast(u16, b);
}
__device__ __forceinline__ float bf2f(u16 u) {
    union { unsigned int i; float f; } v; v.i = ((unsigned int)u) << 16; return v.f;
}

// global -> LDS direct copy, 16B per lane (wave-uniform LDS base + lane*16).
__device__ __forceinline__ void gload16(const u16* g, u16* lds_base) {
    __builtin_amdgcn_global_load_lds(
        (const __attribute__((address_space(1))) unsigned int*)g,
        (__attribute__((address_space(3))) unsigned int*)lds_base,
        16, 0, 0);
}

// ---------- prep: blocks [0,4096) = X f32->bf16 ; blocks [4096,7168) = W transpose ----------
__global__ __launch_bounds__(256) void prep(const float* __restrict__ X, u16* __restrict__ Xb,
                                            const float* __restrict__ W, u16* __restrict__ Wt) {
    __shared__ u16 tile[32][33];
    const int bid = blockIdx.x;
    if (bid < 4096) {
        int i = (bid * 256 + threadIdx.x) * 4;
        float4 v = *(const float4*)(X + i);
        Xb[i + 0] = f2bf(v.x); Xb[i + 1] = f2bf(v.y);
        Xb[i + 2] = f2bf(v.z); Xb[i + 3] = f2bf(v.w);
    } else {
        int bid2 = bid - 4096;
        int n0 = (bid2 % 96) * 32, k0 = (bid2 / 96) * 32;
        int tx = threadIdx.x & 31, ty = threadIdx.x >> 5;
#pragma unroll
        for (int i = 0; i < 4; i++) {
            int k = ty + i * 8;
            tile[k][tx] = f2bf(W[(size_t)(k0 + k) * 3072 + n0 + tx]);
        }
        __syncthreads();
#pragma unroll
        for (int i = 0; i < 4; i++) {
            int n = ty + i * 8;
            Wt[(size_t)(n0 + n) * 1024 + k0 + tx] = tile[tx][n];
        }
    }
}

// ---------- QKV GEMM with fused V-transpose epilogue + XCD-chunked block remap ----------
__global__ __launch_bounds__(256) void qkv_gemm(const u16* __restrict__ A, const u16* __restrict__ Bt,
                                                u16* __restrict__ C, u16* __restrict__ Vtp) {
    __shared__ alignas(16) u16 As[128 * 64];
    __shared__ alignas(16) u16 Bs[128 * 64];
    const int tid = threadIdx.x, l = tid & 63, w = tid >> 6;
    const int fid = blockIdx.x + blockIdx.y * 24;
    const int swz = (fid & 7) * 96 + (fid >> 3);   // bijective: 768 = 8*96
    const int bn = swz >> 5, bm = swz & 31;
    const int wm = w >> 1, wn = w & 1;
    const int c0 = l & 15, g = l >> 4;
    f32x4 acc[4][4] = {};
    for (int kt = 0; kt < 1024; kt += 64) {
        __syncthreads();
#pragma unroll
        for (int n = 0; n < 4; n++) {
            int i = tid + n * 256;
            int r = i >> 3, c = i & 7;
            int cs = c ^ (r & 7);
            u16* dstA = As + (size_t)(w * 64 + n * 256) * 8;
            u16* dstB = Bs + (size_t)(w * 64 + n * 256) * 8;
            gload16(A + (size_t)(bm * 128 + r) * 1024 + kt + cs * 8, dstA);
            gload16(Bt + (size_t)(bn * 128 + r) * 1024 + kt + cs * 8, dstB);
        }
        __syncthreads();
#pragma unroll
        for (int kk = 0; kk < 2; kk++) {
            bf16x8 af[4], bfr[4];
#pragma unroll
            for (int m = 0; m < 4; m++) {
                int row = wm * 64 + m * 16 + c0;
                af[m] = *(const bf16x8*)((const char*)As + row * 128 + (((g + kk * 4) ^ (row & 7)) << 4));
            }
#pragma unroll
            for (int n = 0; n < 4; n++) {
                int row = wn * 64 + n * 16 + c0;
                bfr[n] = *(const bf16x8*)((const char*)Bs + row * 128 + (((g + kk * 4) ^ (row & 7)) << 4));
            }
#pragma unroll
            for (int m = 0; m < 4; m++)
#pragma unroll
                for (int n = 0; n < 4; n++)
                    acc[m][n] = __builtin_amdgcn_mfma_f32_16x16x32_bf16(af[m], bfr[n], acc[m][n], 0, 0, 0);
        }
    }
    if (bn < 16) {
#pragma unroll
        for (int m = 0; m < 4; m++)
#pragma unroll
            for (int n = 0; n < 4; n++)
#pragma unroll
                for (int j = 0; j < 4; j++) {
                    int row = bm * 128 + wm * 64 + m * 16 + 4 * g + j;
                    int col = bn * 128 + wn * 64 + n * 16 + c0;
                    C[(size_t)row * 3072 + col] = f2bf(acc[m][n][j]);
                }
    } else {
        const int h = (bn - 16) * 2 + wn;
#pragma unroll
        for (int m = 0; m < 4; m++) {
            int srow_g = bm * 128 + wm * 64 + m * 16 + 4 * g;   // +j
            int b = srow_g >> 11;
            int srow = srow_g & 2047;
            int sbase = (srow & ~63) + 32 * (m >> 1) + 8 * g + 4 * (m & 1);
#pragma unroll
            for (int n = 0; n < 4; n++) {
                int d = n * 16 + c0;
                u16x4 v;
#pragma unroll
                for (int j = 0; j < 4; j++) v[j] = f2bf(acc[m][n][j]);
                *(u16x4*)(Vtp + ((size_t)(b * 16 + h) * 64 + d) * S_LEN + sbase) = v;
            }
        }
    }
}

// ---------- Flash attention v12b: KVBLK=32, 32KB LDS -> 4 blocks/CU (32 waves).
// FIX vs R14: no runtime-indexed pointer ARRAYS (rule #20 scratch spill) — buffer select
// is pure arithmetic: base = smem + (hf*2 + cur)*2048. ----------
__global__ __launch_bounds__(512, 8) void attn12(const u16* __restrict__ QKV, const u16* __restrict__ Vtp,
                                                 float* __restrict__ outp) {
    __shared__ alignas(16) u16 smem[16384];   // 32KB: [0,8192) K: [hf][buf][2048]; [8192,16384) V
    const int bid = blockIdx.x;
    const int wg = ((bid & 7) << 7) | (bid >> 3);    // 1024 = 8*128, bijective XCD swizzle
    const int tid = threadIdx.x, l = tid & 63, w = tid >> 6;
    const int hf = w >> 2, wsub = w & 3;             // half & wave-within-half
    const int qt = wg & 31, bh = wg >> 5;
    const int b = bh >> 4, h = bh & 15;
    const int c0 = l & 15, g = l >> 4;
    const u16* Qb = QKV + (size_t)b * S_LEN * 3072 + h * 64;
    const u16* Kb = Qb + 1024;
    const u16* Vb = Vtp + (size_t)bh * 64 * S_LEN;
    const int kv0 = hf * 1024;
    const int qrow = qt * 64 + wsub * 16 + c0;

    // staging (per half, 256 threads, ONE chunk per thread per operand):
    // K: 32 rows x 8 chunks (row 128B, chunk^=(key&7)); V: 64 rows x 4 chunks (row 64B, chunk^=((d>>1)&3))
    const int tid_h = tid & 255;
    const int rK = tid_h >> 3, cK = (tid_h & 7) ^ (rK & 7);
    const int rV = tid_h >> 2, cV = (tid_h & 3) ^ ((rV >> 1) & 3);
    const int db = (wsub * 64) * 8;                  // wave-uniform dest offset (u16 units)
    const int kb0 = hf * 2 * 2048;                   // u16 offsets of the two K bufs
    const int vb0 = 8192 + hf * 2 * 2048;

    // LDS read byte-offsets (loop-invariant)
    int koff[4], voff[4];
#pragma unroll
    for (int x = 0; x < 2; x++)
#pragma unroll
        for (int kk = 0; kk < 2; kk++)
            koff[x * 2 + kk] = (x * 16 + c0) * 128 + (((g + 4 * kk) ^ (c0 & 7)) << 4);
#pragma unroll
    for (int n = 0; n < 4; n++) {
        int d = n * 16 + c0;
        voff[n] = d * 64 + ((g ^ ((d >> 1) & 3)) << 4);
    }

    // Q B-frags; fold (1/8)*log2(e)
    bf16x8 qf[2];
    {
        const float qs = 0.125f * 1.44269504f;
#pragma unroll
        for (int kk = 0; kk < 2; kk++) {
            u16x8 v = *(const u16x8*)(Qb + (size_t)qrow * 3072 + kk * 32 + g * 8);
            bf16x8 q;
#pragma unroll
            for (int j = 0; j < 8; j++) q[j] = (__bf16)(bf2f(v[j]) * qs);
            qf[kk] = q;
        }
    }
    bf16x8 vone;
#pragma unroll
    for (int j = 0; j < 8; j++) vone[j] = (__bf16)1.0f;

    float m_r = 0.f;             // baked scheme: sc accumulates S - m_r (per-lane q = c0)
    f32x4 accO[4] = {};
    f32x4 accL = {};

    // prologue: stage tile 0 into buf 0 (arithmetic base select — no pointer arrays)
    gload16(Kb + (size_t)(kv0 + rK) * 3072 + cK * 8, smem + kb0 + db);
    gload16(Vb + (size_t)rV * S_LEN + kv0 + cV * 8, smem + vb0 + db);

    for (int t = 0; t < 32; t++) {
        const int cur = t & 1;
        __syncthreads();  // buf[cur] staged (vmcnt drained at barrier) + prev reads done
        if (t + 1 < 32) {
            const int kvn = kv0 + (t + 1) * 32;
            const int nb = (cur ^ 1) * 2048;
            gload16(Kb + (size_t)(kvn + rK) * 3072 + cK * 8, smem + kb0 + nb + db);
            gload16(Vb + (size_t)rV * S_LEN + kvn + cV * 8, smem + vb0 + nb + db);
        }
        const char* Kc = (const char*)(smem + kb0 + cur * 2048);
        const char* Vc = (const char*)(smem + vb0 + cur * 2048);
        // QK^T (swapped) with C-in = -m_r: sc = S - m_r directly
        f32x4 sc[2];
        const float nm = -m_r;
#pragma unroll
        for (int kb = 0; kb < 2; kb++) { sc[kb][0] = nm; sc[kb][1] = nm; sc[kb][2] = nm; sc[kb][3] = nm; }
        __builtin_amdgcn_s_setprio(1);
#pragma unroll
        for (int kb = 0; kb < 2; kb++)
#pragma unroll
            for (int kk = 0; kk < 2; kk++) {
                bf16x8 kf = *(const bf16x8*)(Kc + koff[kb * 2 + kk]);
                sc[kb] = __builtin_amdgcn_mfma_f32_16x16x32_bf16(kf, qf[kk], sc[kb], 0, 0, 0);
            }
        __builtin_amdgcn_s_setprio(0);
        // V fragment reads (latency hides under softmax)
        bf16x8 vf[4];
#pragma unroll
        for (int n = 0; n < 4; n++)
            vf[n] = *(const bf16x8*)(Vc + voff[n]);
        // lane-local max of baked scores (8 values)
        float m0 = fmaxf(sc[0][0], sc[0][1]);
        float m1 = fmaxf(sc[0][2], sc[0][3]);
        float m2 = fmaxf(sc[1][0], sc[1][1]);
        float m3 = fmaxf(sc[1][2], sc[1][3]);
        float mx = fmaxf(fmaxf(m0, m1), fmaxf(m2, m3));
        // defer-max: rescale only if some lane's local growth exceeds 8 (log2 domain)
        if (!__all(mx <= 8.f)) {
            float mxr = fmaxf(mx, __shfl_xor(mx, 16));
            mxr = fmaxf(mxr, __shfl_xor(mxr, 32));        // per-q full-row baked max
            float adj = fmaxf(mxr, 0.f);
            float alpha = __builtin_amdgcn_exp2f(-adj);
            m_r += adj;
#pragma unroll
            for (int j = 0; j < 4; j++) {
                float aj = __shfl(alpha, 20 * g + j);
                accL[j] *= aj;
#pragma unroll
                for (int n = 0; n < 4; n++) accO[n][j] *= aj;
            }
#pragma unroll
            for (int kb = 0; kb < 2; kb++)
#pragma unroll
                for (int j = 0; j < 4; j++) sc[kb][j] -= adj;
        }
        // P = exp2(baked scores)
#pragma unroll
        for (int kb = 0; kb < 2; kb++)
#pragma unroll
            for (int j = 0; j < 4; j++)
                sc[kb][j] = __builtin_amdgcn_exp2f(sc[kb][j]);
        // PV + l (accL = P @ ones); Vtp perm is 32-granular -> pf lane-local
        __builtin_amdgcn_s_setprio(1);
        {
            bf16x8 pf;
#pragma unroll
            for (int j = 0; j < 4; j++) {
                pf[j]     = (__bf16)sc[0][j];
                pf[j + 4] = (__bf16)sc[1][j];
            }
            accL = __builtin_amdgcn_mfma_f32_16x16x32_bf16(pf, vone, accL, 0, 0, 0);
#pragma unroll
            for (int n = 0; n < 4; n++)
                accO[n] = __builtin_amdgcn_mfma_f32_16x16x32_bf16(pf, vf[n], accO[n], 0, 0, 0);
        }
        __builtin_amdgcn_s_setprio(0);
    }
    // ---- in-block merge: half-1 dumps unnormalized partials into (dead) smem ----
    __syncthreads();
    float* Opart = (float*)smem;             // 64 x 65 f32 = 16.6KB
    float* m1s   = Opart + 64 * 65;          // 64 f32
    float* l1s   = m1s + 64;                 // 64 f32 (total 17.2KB < 32KB)
    if (hf == 1) {
#pragma unroll
        for (int j = 0; j < 4; j++) {
            int rj = wsub * 16 + 4 * g + j;
#pragma unroll
            for (int n = 0; n < 4; n++) Opart[rj * 65 + n * 16 + c0] = accO[n][j];
        }
        if (g == 0) m1s[wsub * 16 + c0] = m_r;
        if (c0 == 0) {
#pragma unroll
            for (int j = 0; j < 4; j++) l1s[wsub * 16 + 4 * g + j] = accL[j];
        }
    }
    __syncthreads();
    if (hf == 0) {
#pragma unroll
        for (int j = 0; j < 4; j++) {
            int rj = wsub * 16 + 4 * g + j;
            float m1v = m1s[rj], l1v = l1s[rj];
            float m0v = __shfl(m_r, 20 * g + j);
            float M = fmaxf(m0v, m1v);
            float a0 = __builtin_amdgcn_exp2f(m0v - M);
            float a1 = __builtin_amdgcn_exp2f(m1v - M);
            float inv = 1.0f / (a0 * accL[j] + a1 * l1v);
            float* op = outp + ((size_t)b * S_LEN + qt * 64 + rj) * DMODEL + h * 64;
#pragma unroll
            for (int n = 0; n < 4; n++)
                op[n * 16 + c0] = (a0 * accO[n][j] + a1 * Opart[rj * 65 + n * 16 + c0]) * inv;
        }
    }
}

extern "C" void kernel_launch(void* const* d_in, const int* in_sizes, int n_in,
                              void* d_out, int out_size, void* d_ws, size_t ws_size,
                              hipStream_t stream) {
    const float* X = (const float*)d_in[0];
    const float* W = (const float*)d_in[1];
    float* out = (float*)d_out;

    u16* Xb  = (u16*)d_ws;                        // 4096*1024 bf16
    u16* Wt  = Xb + (size_t)4096 * 1024;          // 3072*1024 bf16
    u16* QKV = Wt + (size_t)3072 * 1024;          // 4096*3072 bf16 (V third unused)
    u16* Vtp = QKV + (size_t)4096 * 3072;         // 32*64*2048 bf16 (~48MB total)

    prep<<<7168, 256, 0, stream>>>(X, Xb, W, Wt);
    qkv_gemm<<<dim3(24, 32), 256, 0, stream>>>(Xb, Wt, QKV, Vtp);
    attn12<<<1024, 512, 0, stream>>>(QKV, Vtp, out);
}

// Round 17
// 103.346 us; speedup vs baseline: 3.8906x; 1.1898x over previous
//
#include <hip/hip_runtime.h>
#include <hip/hip_bf16.h>
#include <math.h>

typedef __bf16 bf16x8 __attribute__((ext_vector_type(8)));
typedef float f32x4 __attribute__((ext_vector_type(4)));
typedef unsigned short u16x8 __attribute__((ext_vector_type(8)));
typedef unsigned short u16x4 __attribute__((ext_vector_type(4)));
typedef unsigned short u16;

#define S_LEN 2048
#define DMODEL 1024
#define NH 16

__device__ __forceinline__ u16 f2bf(float f) {
    __bf16 b = (__bf16)f;
    return __builtin_bit_cast(u16, b);
}
__device__ __forceinline__ float bf2f(u16 u) {
    union { unsigned int i; float f; } v; v.i = ((unsigned int)u) << 16; return v.f;
}

// global -> LDS direct copy, 16B per lane (wave-uniform LDS base + lane*16).
__device__ __forceinline__ void gload16(const u16* g, u16* lds_base) {
    __builtin_amdgcn_global_load_lds(
        (const __attribute__((address_space(1))) unsigned int*)g,
        (__attribute__((address_space(3))) unsigned int*)lds_base,
        16, 0, 0);
}

// ---------- prep: blocks [0,4096) = X f32->bf16 ; blocks [4096,7168) = W transpose ----------
__global__ __launch_bounds__(256) void prep(const float* __restrict__ X, u16* __restrict__ Xb,
                                            const float* __restrict__ W, u16* __restrict__ Wt) {
    __shared__ u16 tile[32][33];
    const int bid = blockIdx.x;
    if (bid < 4096) {
        int i = (bid * 256 + threadIdx.x) * 4;
        float4 v = *(const float4*)(X + i);
        Xb[i + 0] = f2bf(v.x); Xb[i + 1] = f2bf(v.y);
        Xb[i + 2] = f2bf(v.z); Xb[i + 3] = f2bf(v.w);
    } else {
        int bid2 = bid - 4096;
        int n0 = (bid2 % 96) * 32, k0 = (bid2 / 96) * 32;
        int tx = threadIdx.x & 31, ty = threadIdx.x >> 5;
#pragma unroll
        for (int i = 0; i < 4; i++) {
            int k = ty + i * 8;
            tile[k][tx] = f2bf(W[(size_t)(k0 + k) * 3072 + n0 + tx]);
        }
        __syncthreads();
#pragma unroll
        for (int i = 0; i < 4; i++) {
            int n = ty + i * 8;
            Wt[(size_t)(n0 + n) * 1024 + k0 + tx] = tile[tx][n];
        }
    }
}

// ---------- QKV GEMM with fused V-transpose epilogue + XCD-chunked block remap ----------
__global__ __launch_bounds__(256) void qkv_gemm(const u16* __restrict__ A, const u16* __restrict__ Bt,
                                                u16* __restrict__ C, u16* __restrict__ Vtp) {
    __shared__ alignas(16) u16 As[128 * 64];
    __shared__ alignas(16) u16 Bs[128 * 64];
    const int tid = threadIdx.x, l = tid & 63, w = tid >> 6;
    const int fid = blockIdx.x + blockIdx.y * 24;
    const int swz = (fid & 7) * 96 + (fid >> 3);   // bijective: 768 = 8*96
    const int bn = swz >> 5, bm = swz & 31;
    const int wm = w >> 1, wn = w & 1;
    const int c0 = l & 15, g = l >> 4;
    f32x4 acc[4][4] = {};
    for (int kt = 0; kt < 1024; kt += 64) {
        __syncthreads();
#pragma unroll
        for (int n = 0; n < 4; n++) {
            int i = tid + n * 256;
            int r = i >> 3, c = i & 7;
            int cs = c ^ (r & 7);
            u16* dstA = As + (size_t)(w * 64 + n * 256) * 8;
            u16* dstB = Bs + (size_t)(w * 64 + n * 256) * 8;
            gload16(A + (size_t)(bm * 128 + r) * 1024 + kt + cs * 8, dstA);
            gload16(Bt + (size_t)(bn * 128 + r) * 1024 + kt + cs * 8, dstB);
        }
        __syncthreads();
#pragma unroll
        for (int kk = 0; kk < 2; kk++) {
            bf16x8 af[4], bfr[4];
#pragma unroll
            for (int m = 0; m < 4; m++) {
                int row = wm * 64 + m * 16 + c0;
                af[m] = *(const bf16x8*)((const char*)As + row * 128 + (((g + kk * 4) ^ (row & 7)) << 4));
            }
#pragma unroll
            for (int n = 0; n < 4; n++) {
                int row = wn * 64 + n * 16 + c0;
                bfr[n] = *(const bf16x8*)((const char*)Bs + row * 128 + (((g + kk * 4) ^ (row & 7)) << 4));
            }
#pragma unroll
            for (int m = 0; m < 4; m++)
#pragma unroll
                for (int n = 0; n < 4; n++)
                    acc[m][n] = __builtin_amdgcn_mfma_f32_16x16x32_bf16(af[m], bfr[n], acc[m][n], 0, 0, 0);
        }
    }
    if (bn < 16) {
#pragma unroll
        for (int m = 0; m < 4; m++)
#pragma unroll
            for (int n = 0; n < 4; n++)
#pragma unroll
                for (int j = 0; j < 4; j++) {
                    int row = bm * 128 + wm * 64 + m * 16 + 4 * g + j;
                    int col = bn * 128 + wn * 64 + n * 16 + c0;
                    C[(size_t)row * 3072 + col] = f2bf(acc[m][n][j]);
                }
    } else {
        const int h = (bn - 16) * 2 + wn;
#pragma unroll
        for (int m = 0; m < 4; m++) {
            int srow_g = bm * 128 + wm * 64 + m * 16 + 4 * g;   // +j
            int b = srow_g >> 11;
            int srow = srow_g & 2047;
            int sbase = (srow & ~63) + 32 * (m >> 1) + 8 * g + 4 * (m & 1);
#pragma unroll
            for (int n = 0; n < 4; n++) {
                int d = n * 16 + c0;
                u16x4 v;
#pragma unroll
                for (int j = 0; j < 4; j++) v[j] = f2bf(acc[m][n][j]);
                *(u16x4*)(Vtp + ((size_t)(b * 16 + h) * 64 + d) * S_LEN + sbase) = v;
            }
        }
    }
}

// ---------- Flash attention v11 (champion): attn9 datapath, KV-split x2 IN-BLOCK
// (8 waves / 512 thr: waves 0-3 = KV half 0, waves 4-7 = half 1), in-LDS merge epilogue. ----------
__global__ __launch_bounds__(512, 4) void attn11(const u16* __restrict__ QKV, const u16* __restrict__ Vtp,
                                                 float* __restrict__ outp) {
    __shared__ alignas(16) u16 Ks[2][2][64 * 64];   // [hf][buf][key][d-chunk], chunk^=(key&7)
    __shared__ alignas(16) u16 Vs[2][2][64 * 64];   // [hf][buf][d][pos-chunk], chunk^=(d&7)
    const int bid = blockIdx.x;
    const int wg = ((bid & 7) << 7) | (bid >> 3);    // 1024 = 8*128, bijective XCD swizzle
    const int tid = threadIdx.x, l = tid & 63, w = tid >> 6;
    const int hf = w >> 2, wsub = w & 3;             // half & wave-within-half
    const int qt = wg & 31, bh = wg >> 5;
    const int b = bh >> 4, h = bh & 15;
    const int c0 = l & 15, g = l >> 4;
    const u16* Qb = QKV + (size_t)b * S_LEN * 3072 + h * 64;
    const u16* Kb = Qb + 1024;
    const u16* Vb = Vtp + (size_t)bh * 64 * S_LEN;
    const int kv0 = hf * 1024;
    const int qrow = qt * 64 + wsub * 16 + c0;

    const int tid_h = tid & 255;
    const int r0 = tid_h >> 3, cs0 = (tid_h & 7) ^ (r0 & 7);
    const int i1 = tid_h + 256, r1 = i1 >> 3, cs1 = (i1 & 7) ^ (r1 & 7);
    const int dbA = (wsub * 64) * 8, dbB = (256 + wsub * 64) * 8;

    int off[8];
#pragma unroll
    for (int x = 0; x < 4; x++)
#pragma unroll
        for (int kk = 0; kk < 2; kk++)
            off[x * 2 + kk] = (x * 16 + c0) * 128 + (((g + 4 * kk) ^ (c0 & 7)) << 4);

    bf16x8 qf[2];
    {
        const float qs = 0.125f * 1.44269504f;
#pragma unroll
        for (int kk = 0; kk < 2; kk++) {
            u16x8 v = *(const u16x8*)(Qb + (size_t)qrow * 3072 + kk * 32 + g * 8);
            bf16x8 q;
#pragma unroll
            for (int j = 0; j < 8; j++) q[j] = (__bf16)(bf2f(v[j]) * qs);
            qf[kk] = q;
        }
    }
    bf16x8 vone;
#pragma unroll
    for (int j = 0; j < 8; j++) vone[j] = (__bf16)1.0f;

    float m_r = 0.f;
    f32x4 accO[4] = {};
    f32x4 accL = {};

    gload16(Kb + (size_t)(kv0 + r0) * 3072 + cs0 * 8, Ks[hf][0] + dbA);
    gload16(Kb + (size_t)(kv0 + r1) * 3072 + cs1 * 8, Ks[hf][0] + dbB);
    gload16(Vb + (size_t)r0 * S_LEN + kv0 + cs0 * 8, Vs[hf][0] + dbA);
    gload16(Vb + (size_t)r1 * S_LEN + kv0 + cs1 * 8, Vs[hf][0] + dbB);

    for (int t = 0; t < 16; t++) {
        const int cur = t & 1;
        __syncthreads();
        if (t + 1 < 16) {
            const int kvn = kv0 + (t + 1) * 64;
            gload16(Kb + (size_t)(kvn + r0) * 3072 + cs0 * 8, Ks[hf][cur ^ 1] + dbA);
            gload16(Kb + (size_t)(kvn + r1) * 3072 + cs1 * 8, Ks[hf][cur ^ 1] + dbB);
            gload16(Vb + (size_t)r0 * S_LEN + kvn + cs0 * 8, Vs[hf][cur ^ 1] + dbA);
            gload16(Vb + (size_t)r1 * S_LEN + kvn + cs1 * 8, Vs[hf][cur ^ 1] + dbB);
        }
        const char* Kc = (const char*)Ks[hf][cur];
        const char* Vc = (const char*)Vs[hf][cur];
        f32x4 sc[4];
        const float nm = -m_r;
#pragma unroll
        for (int kb = 0; kb < 4; kb++) { sc[kb][0] = nm; sc[kb][1] = nm; sc[kb][2] = nm; sc[kb][3] = nm; }
        __builtin_amdgcn_s_setprio(1);
#pragma unroll
        for (int kb = 0; kb < 4; kb++)
#pragma unroll
            for (int kk = 0; kk < 2; kk++) {
                bf16x8 kf = *(const bf16x8*)(Kc + off[kb * 2 + kk]);
                sc[kb] = __builtin_amdgcn_mfma_f32_16x16x32_bf16(kf, qf[kk], sc[kb], 0, 0, 0);
            }
        __builtin_amdgcn_s_setprio(0);
        bf16x8 vf[2][4];
#pragma unroll
        for (int kk = 0; kk < 2; kk++)
#pragma unroll
            for (int n = 0; n < 4; n++)
                vf[kk][n] = *(const bf16x8*)(Vc + off[n * 2 + kk]);
        float m0 = fmaxf(fmaxf(sc[0][0], sc[0][1]), sc[0][2]);
        float m1 = fmaxf(fmaxf(sc[0][3], sc[1][0]), sc[1][1]);
        float m2 = fmaxf(fmaxf(sc[1][2], sc[1][3]), sc[2][0]);
        float m3 = fmaxf(fmaxf(sc[2][1], sc[2][2]), sc[2][3]);
        float m4 = fmaxf(fmaxf(sc[3][0], sc[3][1]), sc[3][2]);
        float mx = fmaxf(fmaxf(fmaxf(m0, m1), m2), fmaxf(fmaxf(m3, m4), sc[3][3]));
        if (!__all(mx <= 8.f)) {
            float mxr = fmaxf(mx, __shfl_xor(mx, 16));
            mxr = fmaxf(mxr, __shfl_xor(mxr, 32));
            float adj = fmaxf(mxr, 0.f);
            float alpha = __builtin_amdgcn_exp2f(-adj);
            m_r += adj;
#pragma unroll
            for (int j = 0; j < 4; j++) {
                float aj = __shfl(alpha, 20 * g + j);
                accL[j] *= aj;
#pragma unroll
                for (int n = 0; n < 4; n++) accO[n][j] *= aj;
            }
#pragma unroll
            for (int kb = 0; kb < 4; kb++)
#pragma unroll
                for (int j = 0; j < 4; j++) sc[kb][j] -= adj;
        }
#pragma unroll
        for (int kb = 0; kb < 4; kb++)
#pragma unroll
            for (int j = 0; j < 4; j++)
                sc[kb][j] = __builtin_amdgcn_exp2f(sc[kb][j]);
        __builtin_amdgcn_s_setprio(1);
#pragma unroll
        for (int kk = 0; kk < 2; kk++) {
            bf16x8 pf;
#pragma unroll
            for (int j = 0; j < 4; j++) {
                pf[j]     = (__bf16)sc[2 * kk][j];
                pf[j + 4] = (__bf16)sc[2 * kk + 1][j];
            }
            accL = __builtin_amdgcn_mfma_f32_16x16x32_bf16(pf, vone, accL, 0, 0, 0);
#pragma unroll
            for (int n = 0; n < 4; n++)
                accO[n] = __builtin_amdgcn_mfma_f32_16x16x32_bf16(pf, vf[kk][n], accO[n], 0, 0, 0);
        }
        __builtin_amdgcn_s_setprio(0);
    }
    __syncthreads();
    float* Opart = (float*)&Ks[0][0][0];
    float* m1s   = (float*)&Vs[0][0][0];
    float* l1s   = m1s + 64;
    if (hf == 1) {
#pragma unroll
        for (int j = 0; j < 4; j++) {
            int rj = wsub * 16 + 4 * g + j;
#pragma unroll
            for (int n = 0; n < 4; n++) Opart[rj * 65 + n * 16 + c0] = accO[n][j];
        }
        if (g == 0) m1s[wsub * 16 + c0] = m_r;
        if (c0 == 0) {
#pragma unroll
            for (int j = 0; j < 4; j++) l1s[wsub * 16 + 4 * g + j] = accL[j];
        }
    }
    __syncthreads();
    if (hf == 0) {
#pragma unroll
        for (int j = 0; j < 4; j++) {
            int rj = wsub * 16 + 4 * g + j;
            float m1v = m1s[rj], l1v = l1s[rj];
            float m0v = __shfl(m_r, 20 * g + j);
            float M = fmaxf(m0v, m1v);
            float a0 = __builtin_amdgcn_exp2f(m0v - M);
            float a1 = __builtin_amdgcn_exp2f(m1v - M);
            float inv = 1.0f / (a0 * accL[j] + a1 * l1v);
            float* op = outp + ((size_t)b * S_LEN + qt * 64 + rj) * DMODEL + h * 64;
#pragma unroll
            for (int n = 0; n < 4; n++)
                op[n * 16 + c0] = (a0 * accO[n][j] + a1 * Opart[rj * 65 + n * 16 + c0]) * inv;
        }
    }
}

extern "C" void kernel_launch(void* const* d_in, const int* in_sizes, int n_in,
                              void* d_out, int out_size, void* d_ws, size_t ws_size,
                              hipStream_t stream) {
    const float* X = (const float*)d_in[0];
    const float* W = (const float*)d_in[1];
    float* out = (float*)d_out;

    u16* Xb  = (u16*)d_ws;                        // 4096*1024 bf16
    u16* Wt  = Xb + (size_t)4096 * 1024;          // 3072*1024 bf16
    u16* QKV = Wt + (size_t)3072 * 1024;          // 4096*3072 bf16 (V third unused)
    u16* Vtp = QKV + (size_t)4096 * 3072;         // 32*64*2048 bf16 (~48MB total)

    prep<<<7168, 256, 0, stream>>>(X, Xb, W, Wt);
    qkv_gemm<<<dim3(24, 32), 256, 0, stream>>>(Xb, Wt, QKV, Vtp);
    attn11<<<1024, 512, 0, stream>>>(QKV, Vtp, out);
}

// Round 18
// 98.518 us; speedup vs baseline: 4.0813x; 1.0490x over previous
//
#include <hip/hip_runtime.h>
#include <hip/hip_bf16.h>
#include <math.h>

typedef __bf16 bf16x8 __attribute__((ext_vector_type(8)));
typedef float f32x4 __attribute__((ext_vector_type(4)));
typedef unsigned short u16x8 __attribute__((ext_vector_type(8)));
typedef unsigned short u16x4 __attribute__((ext_vector_type(4)));
typedef unsigned short u16;

#define S_LEN 2048
#define DMODEL 1024
#define NH 16

__device__ __forceinline__ u16 f2bf(float f) {
    __bf16 b = (__bf16)f;
    return __builtin_bit_cast(u16, b);
}
__device__ __forceinline__ float bf2f(u16 u) {
    union { unsigned int i; float f; } v; v.i = ((unsigned int)u) << 16; return v.f;
}

// global -> LDS direct copy, 16B per lane (wave-uniform LDS base + lane*16).
__device__ __forceinline__ void gload16(const u16* g, u16* lds_base) {
    __builtin_amdgcn_global_load_lds(
        (const __attribute__((address_space(1))) unsigned int*)g,
        (__attribute__((address_space(3))) unsigned int*)lds_base,
        16, 0, 0);
}

// ---------- prep: blocks [0,4096) = X f32->bf16 ; blocks [4096,7168) = W transpose ----------
__global__ __launch_bounds__(256) void prep(const float* __restrict__ X, u16* __restrict__ Xb,
                                            const float* __restrict__ W, u16* __restrict__ Wt) {
    __shared__ u16 tile[32][33];
    const int bid = blockIdx.x;
    if (bid < 4096) {
        int i = (bid * 256 + threadIdx.x) * 4;
        float4 v = *(const float4*)(X + i);
        Xb[i + 0] = f2bf(v.x); Xb[i + 1] = f2bf(v.y);
        Xb[i + 2] = f2bf(v.z); Xb[i + 3] = f2bf(v.w);
    } else {
        int bid2 = bid - 4096;
        int n0 = (bid2 % 96) * 32, k0 = (bid2 / 96) * 32;
        int tx = threadIdx.x & 31, ty = threadIdx.x >> 5;
#pragma unroll
        for (int i = 0; i < 4; i++) {
            int k = ty + i * 8;
            tile[k][tx] = f2bf(W[(size_t)(k0 + k) * 3072 + n0 + tx]);
        }
        __syncthreads();
#pragma unroll
        for (int i = 0; i < 4; i++) {
            int n = ty + i * 8;
            Wt[(size_t)(n0 + n) * 1024 + k0 + tx] = tile[tx][n];
        }
    }
}

// ---------- QKV GEMM v2: BK=32 double-buffered, attn11-style 1-barrier/K-tile schedule.
// LDS 32KB total (same occupancy as single-buffer BK=64); loads issued right after the
// barrier drain a full compute-phase later (stale drain). Rows are 64B = 4 chunks;
// swizzle c ^= (r>>1)&3 -> 2-way bank aliasing (free). Fused V epilogue + XCD remap kept. ----------
__global__ __launch_bounds__(256) void qkv_gemm(const u16* __restrict__ A, const u16* __restrict__ Bt,
                                                u16* __restrict__ C, u16* __restrict__ Vtp) {
    __shared__ alignas(16) u16 As[2][128 * 32];
    __shared__ alignas(16) u16 Bs[2][128 * 32];
    const int tid = threadIdx.x, l = tid & 63, w = tid >> 6;
    const int fid = blockIdx.x + blockIdx.y * 24;
    const int swz = (fid & 7) * 96 + (fid >> 3);   // bijective: 768 = 8*96
    const int bn = swz >> 5, bm = swz & 31;
    const int wm = w >> 1, wn = w & 1;
    const int c0 = l & 15, g = l >> 4;

    // staging: per operand 512 chunks of 16B; thread handles chunks {tid, tid+256}
    const int r0 = tid >> 2, c0s = (tid & 3) ^ ((r0 >> 1) & 3);
    const int i1 = tid + 256, r1 = i1 >> 2, c1s = (i1 & 3) ^ ((r1 >> 1) & 3);
    const int db0 = (w * 64) * 8, db1 = (256 + w * 64) * 8;   // wave-uniform dests (u16 units)

    // frag read byte-offsets (loop-invariant): row*64 + ((g ^ ((row>>1)&3)) << 4)
    int aoff[4], boff[4];
#pragma unroll
    for (int m = 0; m < 4; m++) {
        int row = wm * 64 + m * 16 + c0;
        aoff[m] = row * 64 + ((g ^ ((row >> 1) & 3)) << 4);
    }
#pragma unroll
    for (int n = 0; n < 4; n++) {
        int row = wn * 64 + n * 16 + c0;
        boff[n] = row * 64 + ((g ^ ((row >> 1) & 3)) << 4);
    }

    f32x4 acc[4][4] = {};
    // prologue: stage K-tile 0 into buf 0
    gload16(A + (size_t)(bm * 128 + r0) * 1024 + c0s * 8, As[0] + db0);
    gload16(A + (size_t)(bm * 128 + r1) * 1024 + c1s * 8, As[0] + db1);
    gload16(Bt + (size_t)(bn * 128 + r0) * 1024 + c0s * 8, Bs[0] + db0);
    gload16(Bt + (size_t)(bn * 128 + r1) * 1024 + c1s * 8, Bs[0] + db1);

    for (int t = 0; t < 32; t++) {
        const int cur = t & 1;
        __syncthreads();   // buf[cur] staged (stale vmcnt drain) + prev reads of buf[cur^1] done
        if (t + 1 < 32) {
            const int kt = (t + 1) * 32;
            gload16(A + (size_t)(bm * 128 + r0) * 1024 + kt + c0s * 8, As[cur ^ 1] + db0);
            gload16(A + (size_t)(bm * 128 + r1) * 1024 + kt + c1s * 8, As[cur ^ 1] + db1);
            gload16(Bt + (size_t)(bn * 128 + r0) * 1024 + kt + c0s * 8, Bs[cur ^ 1] + db0);
            gload16(Bt + (size_t)(bn * 128 + r1) * 1024 + kt + c1s * 8, Bs[cur ^ 1] + db1);
        }
        const char* Ac = (const char*)As[cur];
        const char* Bc = (const char*)Bs[cur];
        bf16x8 af[4], bfr[4];
#pragma unroll
        for (int m = 0; m < 4; m++) af[m] = *(const bf16x8*)(Ac + aoff[m]);
#pragma unroll
        for (int n = 0; n < 4; n++) bfr[n] = *(const bf16x8*)(Bc + boff[n]);
        __builtin_amdgcn_s_setprio(1);
#pragma unroll
        for (int m = 0; m < 4; m++)
#pragma unroll
            for (int n = 0; n < 4; n++)
                acc[m][n] = __builtin_amdgcn_mfma_f32_16x16x32_bf16(af[m], bfr[n], acc[m][n], 0, 0, 0);
        __builtin_amdgcn_s_setprio(0);
    }
    if (bn < 16) {
#pragma unroll
        for (int m = 0; m < 4; m++)
#pragma unroll
            for (int n = 0; n < 4; n++)
#pragma unroll
                for (int j = 0; j < 4; j++) {
                    int row = bm * 128 + wm * 64 + m * 16 + 4 * g + j;
                    int col = bn * 128 + wn * 64 + n * 16 + c0;
                    C[(size_t)row * 3072 + col] = f2bf(acc[m][n][j]);
                }
    } else {
        // V third: direct permuted-transpose store (4 consecutive spos per (m,n) -> 8B store)
        const int h = (bn - 16) * 2 + wn;
#pragma unroll
        for (int m = 0; m < 4; m++) {
            int srow_g = bm * 128 + wm * 64 + m * 16 + 4 * g;   // +j
            int b = srow_g >> 11;
            int srow = srow_g & 2047;
            int sbase = (srow & ~63) + 32 * (m >> 1) + 8 * g + 4 * (m & 1);
#pragma unroll
            for (int n = 0; n < 4; n++) {
                int d = n * 16 + c0;
                u16x4 v;
#pragma unroll
                for (int j = 0; j < 4; j++) v[j] = f2bf(acc[m][n][j]);
                *(u16x4*)(Vtp + ((size_t)(b * 16 + h) * 64 + d) * S_LEN + sbase) = v;
            }
        }
    }
}

// ---------- Flash attention v11 (champion, unchanged): attn9 datapath, KV-split x2 IN-BLOCK
// (8 waves / 512 thr: waves 0-3 = KV half 0, waves 4-7 = half 1), in-LDS merge epilogue. ----------
__global__ __launch_bounds__(512, 4) void attn11(const u16* __restrict__ QKV, const u16* __restrict__ Vtp,
                                                 float* __restrict__ outp) {
    __shared__ alignas(16) u16 Ks[2][2][64 * 64];   // [hf][buf][key][d-chunk], chunk^=(key&7)
    __shared__ alignas(16) u16 Vs[2][2][64 * 64];   // [hf][buf][d][pos-chunk], chunk^=(d&7)
    const int bid = blockIdx.x;
    const int wg = ((bid & 7) << 7) | (bid >> 3);    // 1024 = 8*128, bijective XCD swizzle
    const int tid = threadIdx.x, l = tid & 63, w = tid >> 6;
    const int hf = w >> 2, wsub = w & 3;             // half & wave-within-half
    const int qt = wg & 31, bh = wg >> 5;
    const int b = bh >> 4, h = bh & 15;
    const int c0 = l & 15, g = l >> 4;
    const u16* Qb = QKV + (size_t)b * S_LEN * 3072 + h * 64;
    const u16* Kb = Qb + 1024;
    const u16* Vb = Vtp + (size_t)bh * 64 * S_LEN;
    const int kv0 = hf * 1024;
    const int qrow = qt * 64 + wsub * 16 + c0;

    const int tid_h = tid & 255;
    const int r0 = tid_h >> 3, cs0 = (tid_h & 7) ^ (r0 & 7);
    const int i1 = tid_h + 256, r1 = i1 >> 3, cs1 = (i1 & 7) ^ (r1 & 7);
    const int dbA = (wsub * 64) * 8, dbB = (256 + wsub * 64) * 8;

    int off[8];
#pragma unroll
    for (int x = 0; x < 4; x++)
#pragma unroll
        for (int kk = 0; kk < 2; kk++)
            off[x * 2 + kk] = (x * 16 + c0) * 128 + (((g + 4 * kk) ^ (c0 & 7)) << 4);

    bf16x8 qf[2];
    {
        const float qs = 0.125f * 1.44269504f;
#pragma unroll
        for (int kk = 0; kk < 2; kk++) {
            u16x8 v = *(const u16x8*)(Qb + (size_t)qrow * 3072 + kk * 32 + g * 8);
            bf16x8 q;
#pragma unroll
            for (int j = 0; j < 8; j++) q[j] = (__bf16)(bf2f(v[j]) * qs);
            qf[kk] = q;
        }
    }
    bf16x8 vone;
#pragma unroll
    for (int j = 0; j < 8; j++) vone[j] = (__bf16)1.0f;

    float m_r = 0.f;
    f32x4 accO[4] = {};
    f32x4 accL = {};

    gload16(Kb + (size_t)(kv0 + r0) * 3072 + cs0 * 8, Ks[hf][0] + dbA);
    gload16(Kb + (size_t)(kv0 + r1) * 3072 + cs1 * 8, Ks[hf][0] + dbB);
    gload16(Vb + (size_t)r0 * S_LEN + kv0 + cs0 * 8, Vs[hf][0] + dbA);
    gload16(Vb + (size_t)r1 * S_LEN + kv0 + cs1 * 8, Vs[hf][0] + dbB);

    for (int t = 0; t < 16; t++) {
        const int cur = t & 1;
        __syncthreads();
        if (t + 1 < 16) {
            const int kvn = kv0 + (t + 1) * 64;
            gload16(Kb + (size_t)(kvn + r0) * 3072 + cs0 * 8, Ks[hf][cur ^ 1] + dbA);
            gload16(Kb + (size_t)(kvn + r1) * 3072 + cs1 * 8, Ks[hf][cur ^ 1] + dbB);
            gload16(Vb + (size_t)r0 * S_LEN + kvn + cs0 * 8, Vs[hf][cur ^ 1] + dbA);
            gload16(Vb + (size_t)r1 * S_LEN + kvn + cs1 * 8, Vs[hf][cur ^ 1] + dbB);
        }
        const char* Kc = (const char*)Ks[hf][cur];
        const char* Vc = (const char*)Vs[hf][cur];
        f32x4 sc[4];
        const float nm = -m_r;
#pragma unroll
        for (int kb = 0; kb < 4; kb++) { sc[kb][0] = nm; sc[kb][1] = nm; sc[kb][2] = nm; sc[kb][3] = nm; }
        __builtin_amdgcn_s_setprio(1);
#pragma unroll
        for (int kb = 0; kb < 4; kb++)
#pragma unroll
            for (int kk = 0; kk < 2; kk++) {
                bf16x8 kf = *(const bf16x8*)(Kc + off[kb * 2 + kk]);
                sc[kb] = __builtin_amdgcn_mfma_f32_16x16x32_bf16(kf, qf[kk], sc[kb], 0, 0, 0);
            }
        __builtin_amdgcn_s_setprio(0);
        bf16x8 vf[2][4];
#pragma unroll
        for (int kk = 0; kk < 2; kk++)
#pragma unroll
            for (int n = 0; n < 4; n++)
                vf[kk][n] = *(const bf16x8*)(Vc + off[n * 2 + kk]);
        float m0 = fmaxf(fmaxf(sc[0][0], sc[0][1]), sc[0][2]);
        float m1 = fmaxf(fmaxf(sc[0][3], sc[1][0]), sc[1][1]);
        float m2 = fmaxf(fmaxf(sc[1][2], sc[1][3]), sc[2][0]);
        float m3 = fmaxf(fmaxf(sc[2][1], sc[2][2]), sc[2][3]);
        float m4 = fmaxf(fmaxf(sc[3][0], sc[3][1]), sc[3][2]);
        float mx = fmaxf(fmaxf(fmaxf(m0, m1), m2), fmaxf(fmaxf(m3, m4), sc[3][3]));
        if (!__all(mx <= 8.f)) {
            float mxr = fmaxf(mx, __shfl_xor(mx, 16));
            mxr = fmaxf(mxr, __shfl_xor(mxr, 32));
            float adj = fmaxf(mxr, 0.f);
            float alpha = __builtin_amdgcn_exp2f(-adj);
            m_r += adj;
#pragma unroll
            for (int j = 0; j < 4; j++) {
                float aj = __shfl(alpha, 20 * g + j);
                accL[j] *= aj;
#pragma unroll
                for (int n = 0; n < 4; n++) accO[n][j] *= aj;
            }
#pragma unroll
            for (int kb = 0; kb < 4; kb++)
#pragma unroll
                for (int j = 0; j < 4; j++) sc[kb][j] -= adj;
        }
#pragma unroll
        for (int kb = 0; kb < 4; kb++)
#pragma unroll
            for (int j = 0; j < 4; j++)
                sc[kb][j] = __builtin_amdgcn_exp2f(sc[kb][j]);
        __builtin_amdgcn_s_setprio(1);
#pragma unroll
        for (int kk = 0; kk < 2; kk++) {
            bf16x8 pf;
#pragma unroll
            for (int j = 0; j < 4; j++) {
                pf[j]     = (__bf16)sc[2 * kk][j];
                pf[j + 4] = (__bf16)sc[2 * kk + 1][j];
            }
            accL = __builtin_amdgcn_mfma_f32_16x16x32_bf16(pf, vone, accL, 0, 0, 0);
#pragma unroll
            for (int n = 0; n < 4; n++)
                accO[n] = __builtin_amdgcn_mfma_f32_16x16x32_bf16(pf, vf[kk][n], accO[n], 0, 0, 0);
        }
        __builtin_amdgcn_s_setprio(0);
    }
    __syncthreads();
    float* Opart = (float*)&Ks[0][0][0];
    float* m1s   = (float*)&Vs[0][0][0];
    float* l1s   = m1s + 64;
    if (hf == 1) {
#pragma unroll
        for (int j = 0; j < 4; j++) {
            int rj = wsub * 16 + 4 * g + j;
#pragma unroll
            for (int n = 0; n < 4; n++) Opart[rj * 65 + n * 16 + c0] = accO[n][j];
        }
        if (g == 0) m1s[wsub * 16 + c0] = m_r;
        if (c0 == 0) {
#pragma unroll
            for (int j = 0; j < 4; j++) l1s[wsub * 16 + 4 * g + j] = accL[j];
        }
    }
    __syncthreads();
    if (hf == 0) {
#pragma unroll
        for (int j = 0; j < 4; j++) {
            int rj = wsub * 16 + 4 * g + j;
            float m1v = m1s[rj], l1v = l1s[rj];
            float m0v = __shfl(m_r, 20 * g + j);
            float M = fmaxf(m0v, m1v);
            float a0 = __builtin_amdgcn_exp2f(m0v - M);
            float a1 = __builtin_amdgcn_exp2f(m1v - M);
            float inv = 1.0f / (a0 * accL[j] + a1 * l1v);
            float* op = outp + ((size_t)b * S_LEN + qt * 64 + rj) * DMODEL + h * 64;
#pragma unroll
            for (int n = 0; n < 4; n++)
                op[n * 16 + c0] = (a0 * accO[n][j] + a1 * Opart[rj * 65 + n * 16 + c0]) * inv;
        }
    }
}

extern "C" void kernel_launch(void* const* d_in, const int* in_sizes, int n_in,
                              void* d_out, int out_size, void* d_ws, size_t ws_size,
                              hipStream_t stream) {
    const float* X = (const float*)d_in[0];
    const float* W = (const float*)d_in[1];
    float* out = (float*)d_out;

    u16* Xb  = (u16*)d_ws;                        // 4096*1024 bf16
    u16* Wt  = Xb + (size_t)4096 * 1024;          // 3072*1024 bf16
    u16* QKV = Wt + (size_t)3072 * 1024;          // 4096*3072 bf16 (V third unused)
    u16* Vtp = QKV + (size_t)4096 * 3072;         // 32*64*2048 bf16 (~48MB total)

    prep<<<7168, 256, 0, stream>>>(X, Xb, W, Wt);
    qkv_gemm<<<dim3(24, 32), 256, 0, stream>>>(Xb, Wt, QKV, Vtp);
    attn11<<<1024, 512, 0, stream>>>(QKV, Vtp, out);
}